// Round 15
// baseline (2054.820 us; speedup 1.0000x reference)
//
#include <hip/hip_runtime.h>
#include <hip/hip_bf16.h>
#include <hip/hip_fp16.h>

// QRNN: B=16, S=2048, D=1024, H=1024.  Inputs fp32, outputs fp32.
// Phase 0: convert X, W -> fp16 in ws
// Phase 1: GEMM G = X16 @ W16^T + b — 256x256 tile, BK=64, SINGLE-buffered LDS
//          (64 KiB -> 2 blocks/CU, cross-block wave-slip does the overlap),
//          m97-style 2-sync/tile loop, BK=64 zero-conflict XOR swizzle (r10),
//          Gray-code fragment reuse, kh-outer MFMA, LDS-staged coalesced C.
// Phase 2: chunked linear scan h_t = z_t f_t + (1-f_t) h_{t-1} (32 chunks x 64), 3 passes

#define BB 16
#define SS 2048
#define DD 1024
#define HH 1024
#define N3 3072
#define CHUNK 64
#define NC (SS/CHUNK)    // 32

#define BM 256
#define BN 256
#define BK 64
#define NKT (DD/BK)      // 16 K-tiles

typedef _Float16 f16x8 __attribute__((ext_vector_type(8)));
typedef float    f32x4 __attribute__((ext_vector_type(4)));

__device__ __forceinline__ float sigm_f(float x) {
    return 1.0f / (1.0f + __expf(-x));
}
__device__ __forceinline__ float tanh_f(float x) {
    float ax = fabsf(x);
    float e  = __expf(2.0f * ax);
    float r  = 1.0f - 2.0f / (e + 1.0f);
    return copysignf(r, x);
}

// ---------------- Phase 0: fp32 -> fp16 convert (8 elems/thread) -------------
__global__ __launch_bounds__(256) void cvt_f32_f16(
    const float* __restrict__ src, __half* __restrict__ dst, int n8)
{
    int i = blockIdx.x * 256 + threadIdx.x;
    if (i >= n8) return;
    const float4* s = (const float4*)src + (size_t)i * 2;
    float4 a = s[0], b = s[1];
    f16x8 v;
    v[0] = (_Float16)a.x; v[1] = (_Float16)a.y; v[2] = (_Float16)a.z; v[3] = (_Float16)a.w;
    v[4] = (_Float16)b.x; v[5] = (_Float16)b.y; v[6] = (_Float16)b.z; v[7] = (_Float16)b.w;
    *((f16x8*)dst + i) = v;
}

// ---------------- GEMM: 256^2, single-buffer, 2 blocks/CU --------------------
__global__ __launch_bounds__(512, 4) void gemm_gates8(
    const __half* __restrict__ Xs,      // [rows][1024] fp16 (slab-local)
    const __half* __restrict__ W16,     // [3072][1024] fp16
    const float*  __restrict__ bias,    // [3072] fp32
    __half* __restrict__ G)             // [rows][3072] fp16
{
    __shared__ __half smem[32768] __attribute__((aligned(16)));   // 64 KiB
    __half* As = smem;            // [256 rows][64 k]
    __half* Bs = smem + 16384;

    const int t   = threadIdx.x;
    const int wid = t >> 6;       // 0..7
    const int l   = t & 63;
    const int m0  = blockIdx.x * BM;
    const int n0  = blockIdx.y * BN;
    const int wr  = wid >> 2;     // 0..1 (M)
    const int wc  = wid & 3;      // 0..3 (N)
    const int cl  = l & 15;
    const int kg  = l >> 4;
    const int cs  = cl & 7;       // read-side swizzle key (row&7 == cl&7)

    f32x4 acc[8][4];
    #pragma unroll
    for (int m = 0; m < 8; ++m)
        #pragma unroll
        for (int n = 0; n < 4; ++n)
            acc[m][n] = f32x4{0.f, 0.f, 0.f, 0.f};

    // staging (r10-verified): issue j covers rows j*64..j*64+63; lane -> row
    // j*64 + wid*8 + l/8.  T2 write-side: global 16B-chunk = (l&7)^(row&7);
    // LDS dest linear (wave-uniform base + lane*16B).
    const int srow = wid * 8 + (l >> 3);
    const int scol = (((l & 7) ^ ((l >> 3) & 7)) * 8);
    const __half* Xb = Xs  + (size_t)(m0 + srow) * DD + scol;
    const __half* Wb = W16 + (size_t)(n0 + srow) * DD + scol;

#define ISSUE_A(j, kt) \
    __builtin_amdgcn_global_load_lds( \
        (const __attribute__((address_space(1))) void*)(Xb + (size_t)(j) * 64 * DD + (kt) * BK), \
        (__attribute__((address_space(3))) void*)(&As[(j) * 4096 + wid * 512]), 16, 0, 0)
#define ISSUE_B(j, kt) \
    __builtin_amdgcn_global_load_lds( \
        (const __attribute__((address_space(1))) void*)(Wb + (size_t)(j) * 64 * DD + (kt) * BK), \
        (__attribute__((address_space(3))) void*)(&Bs[(j) * 4096 + wid * 512]), 16, 0, 0)

    // fragment reads (T2 read-side: chunk = (kh*4+kg) ^ (row&7), row&7 == cs)
#define READ_A(ad, rh) \
    _Pragma("unroll") \
    for (int i = 0; i < 4; ++i) \
        _Pragma("unroll") \
        for (int kh = 0; kh < 2; ++kh) \
            ad[i][kh] = *(const f16x8*)(As + ((wr * 128 + ((rh) * 4 + i) * 16 + cl) * BK \
                                              + (((kh * 4 + kg) ^ cs) * 8)))
#define READ_B(bd, ch) \
    _Pragma("unroll") \
    for (int j = 0; j < 2; ++j) \
        _Pragma("unroll") \
        for (int kh = 0; kh < 2; ++kh) \
            bd[j][kh] = *(const f16x8*)(Bs + ((wc * 64 + ((ch) * 2 + j) * 16 + cl) * BK \
                                              + (((kh * 4 + kg) ^ cs) * 8)))

    // MFMA cluster: kh outer -> 8 independent MFMAs between RAW partners
#define MFMA_Q(ad, rh, ch, bd) \
    asm volatile("s_waitcnt lgkmcnt(0)" ::: "memory"); \
    __builtin_amdgcn_sched_barrier(0); \
    __builtin_amdgcn_s_setprio(1); \
    _Pragma("unroll") \
    for (int kh = 0; kh < 2; ++kh) \
        _Pragma("unroll") \
        for (int i = 0; i < 4; ++i) \
            _Pragma("unroll") \
            for (int j = 0; j < 2; ++j) \
                acc[(rh) * 4 + i][(ch) * 2 + j] = __builtin_amdgcn_mfma_f32_16x16x32_f16( \
                    ad[i][kh], bd[j][kh], acc[(rh) * 4 + i][(ch) * 2 + j], 0, 0, 0); \
    __builtin_amdgcn_s_setprio(0); \
    __builtin_amdgcn_sched_barrier(0)

    for (int kt = 0; kt < NKT; ++kt) {
        // stage tile kt (8 issues/thread); __syncthreads drains vmcnt ->
        // tile visible.  With 2 blocks/CU the other block computes during
        // this block's drain (r6 mechanism).
        ISSUE_A(0, kt); ISSUE_A(1, kt); ISSUE_A(2, kt); ISSUE_A(3, kt);
        ISSUE_B(0, kt); ISSUE_B(1, kt); ISSUE_B(2, kt); ISSUE_B(3, kt);
        __syncthreads();

        f16x8 a0[4][2], a1[4][2], b0[2][2], b1[2][2];

        // Gray-code quadrants, relaxed (no intra-tile barriers)
        READ_A(a0, 0); READ_B(b0, 0);
        MFMA_Q(a0, 0, 0, b0);

        READ_B(b1, 1);
        MFMA_Q(a0, 0, 1, b1);

        READ_A(a1, 1);
        MFMA_Q(a1, 1, 1, b1);

        MFMA_Q(a1, 1, 0, b0);

        __syncthreads();   // all reads done before next tile's DMA overwrites
    }
#undef MFMA_Q
#undef READ_A
#undef READ_B
#undef ISSUE_A
#undef ISSUE_B

    // ---- epilogue: LDS-staged coalesced C-store (4 rounds x 64 rows, r10-verified)
    // pitch 264 halves; C/D layout col = lane&15, row = (lane>>4)*4 + reg
    __half* sh = smem;          // 64*264 = 16896 halves <= 32768
    const int bcol0 = n0 + wc * 64 + cl;
    float bv[4];
    #pragma unroll
    for (int fc = 0; fc < 4; ++fc) bv[fc] = bias[bcol0 + fc * 16];

    const int row_l = t >> 3;       // 0..63
    const int chunk = t & 7;        // 64B chunks

    #pragma unroll
    for (int r = 0; r < 4; ++r) {
        if (wr == (r >> 1)) {
            #pragma unroll
            for (int f4 = 0; f4 < 4; ++f4) {
                const int fr = (r & 1) * 4 + f4;
                #pragma unroll
                for (int fc = 0; fc < 4; ++fc) {
                    #pragma unroll
                    for (int i = 0; i < 4; ++i) {
                        sh[(f4 * 16 + kg * 4 + i) * 264 + wc * 64 + fc * 16 + cl] =
                            __float2half(acc[fr][fc][i] + bv[fc]);
                    }
                }
            }
        }
        __syncthreads();
        {
            const __half* src = sh + row_l * 264 + chunk * 32;
            __half* dst = G + (size_t)(m0 + r * 64 + row_l) * N3 + n0 + chunk * 32;
            #pragma unroll
            for (int k = 0; k < 4; ++k)
                *(f16x8*)(dst + k * 8) = *(const f16x8*)(src + k * 8);
        }
        __syncthreads();
    }
}

// ---------------- Pass 1: per-chunk local scan -> (A, F) ---------------------
__global__ __launch_bounds__(256) void scan_pass1(
    const __half* __restrict__ G,
    float* __restrict__ Ac, float* __restrict__ Fc)
{
    const int flat = blockIdx.x * 256 + threadIdx.x;
    const int h  = flat & (HH - 1);
    const int c  = (flat >> 10) & (NC - 1);
    const int lb = flat >> 15;

    const __half* g = G + (size_t)(lb * SS + c * CHUNK) * N3 + h;
    float A = 0.f, F = 1.f;
    for (int s = 0; s < CHUNK; ++s) {
        float z = __half2float(g[0]);
        float f = __half2float(g[HH]);
        g += N3;
        float ft = sigm_f(f);
        float fp = 1.f - ft;
        A = tanh_f(z) * ft + fp * A;
        F *= fp;
    }
    Ac[flat] = A;
    Fc[flat] = F;
}

// ---------------- Pass 2: sequential chunk combine, emit h_in + c_last -------
__global__ __launch_bounds__(256) void scan_pass2(
    const float* __restrict__ Ac, const float* __restrict__ Fc,
    float* __restrict__ Hin, float* __restrict__ c_last)
{
    const int flat = blockIdx.x * 256 + threadIdx.x;   // lb*HH + h
    const int lb = flat >> 10;
    const int h  = flat & (HH - 1);
    float hc = 0.f;
    for (int c = 0; c < NC; ++c) {
        const size_t idx = (size_t)(lb * NC + c) * HH + h;
        Hin[idx] = hc;
        hc = Ac[idx] + Fc[idx] * hc;
    }
    c_last[flat] = hc;
}

// ---------------- Pass 3: replay with correct h_in, fuse output gate ---------
__global__ __launch_bounds__(256) void scan_pass3(
    const __half* __restrict__ G, const float* __restrict__ Hin,
    float* __restrict__ out)
{
    const int flat = blockIdx.x * 256 + threadIdx.x;
    const int h  = flat & (HH - 1);
    const int c  = (flat >> 10) & (NC - 1);
    const int lb = flat >> 15;

    const __half* g = G + (size_t)(lb * SS + c * CHUNK) * N3 + h;
    float* o = out + (size_t)(lb * SS + c * CHUNK) * HH + h;
    float hc = Hin[flat];
    for (int s = 0; s < CHUNK; ++s) {
        float z  = __half2float(g[0]);
        float f  = __half2float(g[HH]);
        float og = __half2float(g[2 * HH]);
        g += N3;
        float ft = sigm_f(f);
        hc = tanh_f(z) * ft + (1.f - ft) * hc;
        *o = hc * sigm_f(og);
        o += HH;
    }
}

extern "C" void kernel_launch(void* const* d_in, const int* in_sizes, int n_in,
                              void* d_out, int out_size, void* d_ws, size_t ws_size,
                              hipStream_t stream) {
    // re-key inputs by element count for order safety
    const float* X    = (const float*)d_in[0];
    const float* W    = (const float*)d_in[1];
    const float* bias = (const float*)d_in[2];
    for (int i = 0; i < n_in && i < 3; ++i) {
        if      (in_sizes[i] == BB * SS * DD) X    = (const float*)d_in[i];
        else if (in_sizes[i] == N3 * DD)      W    = (const float*)d_in[i];
        else if (in_sizes[i] == N3)           bias = (const float*)d_in[i];
    }
    float* out = (float*)d_out;                           // [B,S,H] ++ [B,1,H] fp32
    float* c_last_base = out + (size_t)BB * SS * HH;

    // ws layout: W16 | X16(nb) | G(nb) | Ac/Fc/Hin(nb)
    const size_t w16_b   = (size_t)N3 * DD * sizeof(__half);          //  6.29 MB
    const size_t per_b_x = (size_t)SS * DD * sizeof(__half);          //  4.19 MB
    const size_t per_b_g = (size_t)SS * N3 * sizeof(__half);          // 12.58 MB
    const size_t per_b_s = (size_t)NC * HH * sizeof(float) * 3;       //  0.39 MB
    int nb = 1;
    for (int cand = BB; cand >= 1; --cand) {
        if (w16_b + (size_t)cand * (per_b_x + per_b_g + per_b_s) <= ws_size) {
            nb = cand; break;
        }
    }
    if (nb > 8) nb = 8;   // 2 slabs: G+X16+W16 ~140 MB stays L3-resident

    __half* W16 = (__half*)d_ws;
    __half* X16 = (__half*)((char*)W16 + w16_b);
    __half* G   = (__half*)((char*)X16 + (size_t)nb * per_b_x);
    float*  Ac  = (float*)((char*)G + (size_t)nb * per_b_g);
    float*  Fc  = Ac + (size_t)nb * NC * HH;
    float*  Hin = Fc + (size_t)nb * NC * HH;

    // W convert (once)
    {
        const int n8 = (N3 * DD) / 8;
        cvt_f32_f16<<<(n8 + 255) / 256, 256, 0, stream>>>(W, W16, n8);
    }

    for (int b0 = 0; b0 < BB; b0 += nb) {
        const int bs = (b0 + nb <= BB) ? nb : (BB - b0);

        const int n8x = (bs * SS * DD) / 8;
        cvt_f32_f16<<<(n8x + 255) / 256, 256, 0, stream>>>(
            X + (size_t)b0 * SS * DD, X16, n8x);

        dim3 gg(bs * (SS / BM), N3 / BN);   // (bs*8, 12)
        gemm_gates8<<<gg, 512, 0, stream>>>(X16, W16, bias, G);

        scan_pass1<<<(bs * NC * HH) / 256, 256, 0, stream>>>(G, Ac, Fc);
        scan_pass2<<<(bs * HH) / 256, 256, 0, stream>>>(Ac, Fc, Hin,
                                                        c_last_base + (size_t)b0 * HH);
        scan_pass3<<<(bs * NC * HH) / 256, 256, 0, stream>>>(G, Hin,
                                                             out + (size_t)b0 * SS * HH);
    }
}

// Round 17
// 413.595 us; speedup vs baseline: 4.9682x; 4.9682x over previous
//
#include <hip/hip_runtime.h>
#include <hip/hip_bf16.h>
#include <hip/hip_fp16.h>

// QRNN: B=16, S=2048, D=1024, H=1024.  Inputs fp32, outputs fp32.
// Phase 0: convert X, W -> fp16 in ws
// Phase 1: GEMM G = X16 @ W16^T + b — 256x256 tile, BK=64, counted-vmcnt dbuf,
//          2 barriers/K-tile (boundary + tile-end), T2 XOR swizzle, Gray-code
//          fragment reuse, kh-outer MFMA, LDS-staged coalesced epilogue.
//          [Session-best configuration, r10: 415 µs total, GEMM 137 µs/dispatch]
// Phase 2: chunked linear scan h_t = z_t f_t + (1-f_t) h_{t-1} (32 chunks x 64), 3 passes

#define BB 16
#define SS 2048
#define DD 1024
#define HH 1024
#define N3 3072
#define CHUNK 64
#define NC (SS/CHUNK)    // 32

#define BM 256
#define BN 256
#define BK 64
#define NKT (DD/BK)      // 16 K-tiles

typedef _Float16 f16x8 __attribute__((ext_vector_type(8)));
typedef float    f32x4 __attribute__((ext_vector_type(4)));

__device__ __forceinline__ float sigm_f(float x) {
    return 1.0f / (1.0f + __expf(-x));
}
__device__ __forceinline__ float tanh_f(float x) {
    float ax = fabsf(x);
    float e  = __expf(2.0f * ax);
    float r  = 1.0f - 2.0f / (e + 1.0f);
    return copysignf(r, x);
}

// ---------------- Phase 0: fp32 -> fp16 convert (8 elems/thread) -------------
__global__ __launch_bounds__(256) void cvt_f32_f16(
    const float* __restrict__ src, __half* __restrict__ dst, int n8)
{
    int i = blockIdx.x * 256 + threadIdx.x;
    if (i >= n8) return;
    const float4* s = (const float4*)src + (size_t)i * 2;
    float4 a = s[0], b = s[1];
    f16x8 v;
    v[0] = (_Float16)a.x; v[1] = (_Float16)a.y; v[2] = (_Float16)a.z; v[3] = (_Float16)a.w;
    v[4] = (_Float16)b.x; v[5] = (_Float16)b.y; v[6] = (_Float16)b.z; v[7] = (_Float16)b.w;
    *((f16x8*)dst + i) = v;
}

// ---------------- GEMM: 256^2, 2-barrier/K-tile, swizzled, coalesced C -------
__global__ __launch_bounds__(512) void gemm_gates8(
    const __half* __restrict__ Xs,      // [rows][1024] fp16 (slab-local)
    const __half* __restrict__ W16,     // [3072][1024] fp16
    const float*  __restrict__ bias,    // [3072] fp32
    __half* __restrict__ G)             // [rows][3072] fp16
{
    __shared__ __half As[2][BM * BK] __attribute__((aligned(16)));  // 64 KiB
    __shared__ __half Bs[2][BN * BK] __attribute__((aligned(16)));  // 64 KiB

    const int t   = threadIdx.x;
    const int wid = t >> 6;       // 0..7
    const int l   = t & 63;
    const int m0  = blockIdx.x * BM;
    const int n0  = blockIdx.y * BN;
    const int wr  = wid >> 2;     // 0..1 (M)
    const int wc  = wid & 3;      // 0..3 (N)
    const int cl  = l & 15;
    const int kg  = l >> 4;
    const int cs  = cl & 7;       // read-side swizzle key (row&7 == cl&7)

    f32x4 acc[8][4];
    #pragma unroll
    for (int m = 0; m < 8; ++m)
        #pragma unroll
        for (int n = 0; n < 4; ++n)
            acc[m][n] = f32x4{0.f, 0.f, 0.f, 0.f};

    // staging: issue j covers rows j*64..j*64+63; lane -> row j*64+wid*8+l/8.
    // T2 write-side: global 16B-chunk = (l&7) ^ (row&7); LDS dest linear.
    const int srow = wid * 8 + (l >> 3);
    const int scol = (((l & 7) ^ ((l >> 3) & 7)) * 8);
    const __half* Xb = Xs  + (size_t)(m0 + srow) * DD + scol;
    const __half* Wb = W16 + (size_t)(n0 + srow) * DD + scol;

#define ISSUE_A(slot, j, kt) \
    __builtin_amdgcn_global_load_lds( \
        (const __attribute__((address_space(1))) void*)(Xb + (size_t)(j) * 64 * DD + (kt) * BK), \
        (__attribute__((address_space(3))) void*)(&As[slot][(j) * 4096 + wid * 512]), 16, 0, 0)
#define ISSUE_B(slot, j, kt) \
    __builtin_amdgcn_global_load_lds( \
        (const __attribute__((address_space(1))) void*)(Wb + (size_t)(j) * 64 * DD + (kt) * BK), \
        (__attribute__((address_space(3))) void*)(&Bs[slot][(j) * 4096 + wid * 512]), 16, 0, 0)

    // fragment loads (T2 read-side: chunk = (kh*4+kg) ^ (row&7), row&7 == cs)
#define READ_A(rh) \
    _Pragma("unroll") \
    for (int i = 0; i < 4; ++i) \
        _Pragma("unroll") \
        for (int kh = 0; kh < 2; ++kh) \
            a[i][kh] = *(const f16x8*)(Ab + ((wr * 128 + ((rh) * 4 + i) * 16 + cl) * BK \
                                             + (((kh * 4 + kg) ^ cs) * 8)))
#define READ_B(bd, ch) \
    _Pragma("unroll") \
    for (int j = 0; j < 2; ++j) \
        _Pragma("unroll") \
        for (int kh = 0; kh < 2; ++kh) \
            bd[j][kh] = *(const f16x8*)(Bb + ((wc * 64 + ((ch) * 2 + j) * 16 + cl) * BK \
                                              + (((kh * 4 + kg) ^ cs) * 8)))

    // wait own ds_reads, then MFMA cluster (kh outer: 8 indep MFMAs between
    // successive updates of the same accumulator). No per-phase barriers.
#define WAIT_MFMA(rh, ch, bd) \
    asm volatile("s_waitcnt lgkmcnt(0)" ::: "memory"); \
    __builtin_amdgcn_sched_barrier(0); \
    __builtin_amdgcn_s_setprio(1); \
    _Pragma("unroll") \
    for (int kh = 0; kh < 2; ++kh) \
        _Pragma("unroll") \
        for (int i = 0; i < 4; ++i) \
            _Pragma("unroll") \
            for (int j = 0; j < 2; ++j) \
                acc[(rh) * 4 + i][(ch) * 2 + j] = __builtin_amdgcn_mfma_f32_16x16x32_f16( \
                    a[i][kh], bd[j][kh], acc[(rh) * 4 + i][(ch) * 2 + j], 0, 0, 0); \
    __builtin_amdgcn_s_setprio(0)

    // prologue: stage tile 0 into slot 0
    ISSUE_A(0, 0, 0); ISSUE_A(0, 1, 0); ISSUE_A(0, 2, 0); ISSUE_A(0, 3, 0);
    ISSUE_B(0, 0, 0); ISSUE_B(0, 1, 0); ISSUE_B(0, 2, 0); ISSUE_B(0, 3, 0);

    for (int kt = 0; kt < NKT; ++kt) {
        const int cur = kt & 1, nxt = cur ^ 1;
        const __half* Ab = As[cur];
        const __half* Bb = Bs[cur];

        // boundary: issue A-half of next tile, counted wait, sync
        if (kt + 1 < NKT) {
            ISSUE_A(nxt, 0, kt + 1); ISSUE_A(nxt, 1, kt + 1);
            ISSUE_A(nxt, 2, kt + 1); ISSUE_A(nxt, 3, kt + 1);
            asm volatile("s_waitcnt vmcnt(4)" ::: "memory");
        } else {
            asm volatile("s_waitcnt vmcnt(0)" ::: "memory");
        }
        __builtin_amdgcn_s_barrier();

        f16x8 a[4][2], b0[2][2], b1[2][2];

        // P0: read A(rh0)+B(ch0), compute Q(0,0)
        READ_A(0); READ_B(b0, 0);
        WAIT_MFMA(0, 0, b0);

        // P1: read B(ch1); stage B-half of next tile; Q(0,1)
        READ_B(b1, 1);
        if (kt + 1 < NKT) {
            ISSUE_B(nxt, 0, kt + 1); ISSUE_B(nxt, 1, kt + 1);
            ISSUE_B(nxt, 2, kt + 1); ISSUE_B(nxt, 3, kt + 1);
        }
        WAIT_MFMA(0, 1, b1);

        // P2: read A(rh1), reuse b1 -> Q(1,1)
        READ_A(1);
        WAIT_MFMA(1, 1, b1);

        // P3: reuse a + b0 -> Q(1,0), no reads
        WAIT_MFMA(1, 0, b0);

        // tile-end: all reads of cur slot done before next boundary's DMA
        __builtin_amdgcn_s_barrier();
    }
#undef WAIT_MFMA
#undef READ_A
#undef READ_B
#undef ISSUE_A
#undef ISSUE_B

    // ---- epilogue: LDS-staged coalesced C-store (reuse As, 4 rounds x 64 rows)
    // pitch 264 halves (528B): kg-groups land 16 banks apart -> <=4-way on write
    __half* sh = &As[0][0];     // need 64*264 = 16896 halves <= 32768 available
    const int bcol0 = n0 + wc * 64 + cl;
    float bv[4];
    #pragma unroll
    for (int fc = 0; fc < 4; ++fc) bv[fc] = bias[bcol0 + fc * 16];

    const int row_l = t >> 3;       // 0..63
    const int chunk = t & 7;        // 64B chunks

    #pragma unroll
    for (int r = 0; r < 4; ++r) {
        if (wr == (r >> 1)) {
            #pragma unroll
            for (int f4 = 0; f4 < 4; ++f4) {
                const int fr = (r & 1) * 4 + f4;
                #pragma unroll
                for (int fc = 0; fc < 4; ++fc) {
                    #pragma unroll
                    for (int i = 0; i < 4; ++i) {
                        sh[(f4 * 16 + kg * 4 + i) * 264 + wc * 64 + fc * 16 + cl] =
                            __float2half(acc[fr][fc][i] + bv[fc]);
                    }
                }
            }
        }
        __builtin_amdgcn_s_barrier();
        {
            const __half* src = sh + row_l * 264 + chunk * 32;
            __half* dst = G + (size_t)(m0 + r * 64 + row_l) * N3 + n0 + chunk * 32;
            #pragma unroll
            for (int k = 0; k < 4; ++k)
                *(f16x8*)(dst + k * 8) = *(const f16x8*)(src + k * 8);
        }
        __builtin_amdgcn_s_barrier();
    }
}

// ---------------- Pass 1: per-chunk local scan -> (A, F) ---------------------
__global__ __launch_bounds__(256) void scan_pass1(
    const __half* __restrict__ G,
    float* __restrict__ Ac, float* __restrict__ Fc)
{
    const int flat = blockIdx.x * 256 + threadIdx.x;
    const int h  = flat & (HH - 1);
    const int c  = (flat >> 10) & (NC - 1);
    const int lb = flat >> 15;

    const __half* g = G + (size_t)(lb * SS + c * CHUNK) * N3 + h;
    float A = 0.f, F = 1.f;
    for (int s = 0; s < CHUNK; ++s) {
        float z = __half2float(g[0]);
        float f = __half2float(g[HH]);
        g += N3;
        float ft = sigm_f(f);
        float fp = 1.f - ft;
        A = tanh_f(z) * ft + fp * A;
        F *= fp;
    }
    Ac[flat] = A;
    Fc[flat] = F;
}

// ---------------- Pass 2: sequential chunk combine, emit h_in + c_last -------
__global__ __launch_bounds__(256) void scan_pass2(
    const float* __restrict__ Ac, const float* __restrict__ Fc,
    float* __restrict__ Hin, float* __restrict__ c_last)
{
    const int flat = blockIdx.x * 256 + threadIdx.x;   // lb*HH + h
    const int lb = flat >> 10;
    const int h  = flat & (HH - 1);
    float hc = 0.f;
    for (int c = 0; c < NC; ++c) {
        const size_t idx = (size_t)(lb * NC + c) * HH + h;
        Hin[idx] = hc;
        hc = Ac[idx] + Fc[idx] * hc;
    }
    c_last[flat] = hc;
}

// ---------------- Pass 3: replay with correct h_in, fuse output gate ---------
__global__ __launch_bounds__(256) void scan_pass3(
    const __half* __restrict__ G, const float* __restrict__ Hin,
    float* __restrict__ out)
{
    const int flat = blockIdx.x * 256 + threadIdx.x;
    const int h  = flat & (HH - 1);
    const int c  = (flat >> 10) & (NC - 1);
    const int lb = flat >> 15;

    const __half* g = G + (size_t)(lb * SS + c * CHUNK) * N3 + h;
    float* o = out + (size_t)(lb * SS + c * CHUNK) * HH + h;
    float hc = Hin[flat];
    for (int s = 0; s < CHUNK; ++s) {
        float z  = __half2float(g[0]);
        float f  = __half2float(g[HH]);
        float og = __half2float(g[2 * HH]);
        g += N3;
        float ft = sigm_f(f);
        hc = tanh_f(z) * ft + (1.f - ft) * hc;
        *o = hc * sigm_f(og);
        o += HH;
    }
}

extern "C" void kernel_launch(void* const* d_in, const int* in_sizes, int n_in,
                              void* d_out, int out_size, void* d_ws, size_t ws_size,
                              hipStream_t stream) {
    // re-key inputs by element count for order safety
    const float* X    = (const float*)d_in[0];
    const float* W    = (const float*)d_in[1];
    const float* bias = (const float*)d_in[2];
    for (int i = 0; i < n_in && i < 3; ++i) {
        if      (in_sizes[i] == BB * SS * DD) X    = (const float*)d_in[i];
        else if (in_sizes[i] == N3 * DD)      W    = (const float*)d_in[i];
        else if (in_sizes[i] == N3)           bias = (const float*)d_in[i];
    }
    float* out = (float*)d_out;                           // [B,S,H] ++ [B,1,H] fp32
    float* c_last_base = out + (size_t)BB * SS * HH;

    // ws layout: W16 | X16(nb) | G(nb) | Ac/Fc/Hin(nb)
    const size_t w16_b   = (size_t)N3 * DD * sizeof(__half);          //  6.29 MB
    const size_t per_b_x = (size_t)SS * DD * sizeof(__half);          //  4.19 MB
    const size_t per_b_g = (size_t)SS * N3 * sizeof(__half);          // 12.58 MB
    const size_t per_b_s = (size_t)NC * HH * sizeof(float) * 3;       //  0.39 MB
    int nb = 1;
    for (int cand = BB; cand >= 1; --cand) {
        if (w16_b + (size_t)cand * (per_b_x + per_b_g + per_b_s) <= ws_size) {
            nb = cand; break;
        }
    }
    if (nb > 8) nb = 8;   // 2 slabs: exact 768-block GEMM rounds + ~L3-resident G

    __half* W16 = (__half*)d_ws;
    __half* X16 = (__half*)((char*)W16 + w16_b);
    __half* G   = (__half*)((char*)X16 + (size_t)nb * per_b_x);
    float*  Ac  = (float*)((char*)G + (size_t)nb * per_b_g);
    float*  Fc  = Ac + (size_t)nb * NC * HH;
    float*  Hin = Fc + (size_t)nb * NC * HH;

    // W convert (once)
    {
        const int n8 = (N3 * DD) / 8;
        cvt_f32_f16<<<(n8 + 255) / 256, 256, 0, stream>>>(W, W16, n8);
    }

    for (int b0 = 0; b0 < BB; b0 += nb) {
        const int bs = (b0 + nb <= BB) ? nb : (BB - b0);

        const int n8x = (bs * SS * DD) / 8;
        cvt_f32_f16<<<(n8x + 255) / 256, 256, 0, stream>>>(
            X + (size_t)b0 * SS * DD, X16, n8x);

        dim3 gg(bs * (SS / BM), N3 / BN);   // (bs*8, 12)
        gemm_gates8<<<gg, 512, 0, stream>>>(X16, W16, bias, G);

        scan_pass1<<<(bs * NC * HH) / 256, 256, 0, stream>>>(G, Ac, Fc);
        scan_pass2<<<(bs * HH) / 256, 256, 0, stream>>>(Ac, Fc, Hin,
                                                        c_last_base + (size_t)b0 * HH);
        scan_pass3<<<(bs * NC * HH) / 256, 256, 0, stream>>>(G, Hin,
                                                             out + (size_t)b0 * SS * HH);
    }
}